// Round 11
// baseline (389.816 us; speedup 1.0000x reference)
//
#include <hip/hip_runtime.h>
#include <hip/hip_fp16.h>
#include <math.h>

#define DI 384
#define NSEQ 256
#define BB 64
#define DOUT 512
#define SID 73920
#define EPSV 1e-5f

// plane strides (in shorts) for the 2-plane fp16 operand sets
#define PS3 (BB * 147456)  // 384x384 mats
#define PSZ (BB * 98304)   // 384x256 mats
#define PSW (BB * 65536)   // 256x256 mats

typedef float f32x4 __attribute__((ext_vector_type(4)));
typedef short s16x8 __attribute__((ext_vector_type(8)));
typedef _Float16 f16x8 __attribute__((ext_vector_type(8)));

__device__ __forceinline__ unsigned splitpair_h(float a, float c, float& ra,
                                                float& rc) {
  __half2 h = __float22half2_rn(make_float2(a, c));
  unsigned u;
  __builtin_memcpy(&u, &h, 4);
  ra = a - __low2float(h);
  rc = c - __high2float(h);
  return u;
}

__device__ __forceinline__ unsigned packh2(float a, float c) {
  __half2 h = __float22half2_rn(make_float2(a, c));
  unsigned u;
  __builtin_memcpy(&u, &h, 4);
  return u;
}

// split float4 -> 4 hi + 4 mid fp16, two 8B stores
__device__ __forceinline__ void split4_store(float4 v, short* hi, short* mid) {
  float ra, rc;
  unsigned h01 = splitpair_h(v.x, v.y, ra, rc);
  unsigned m01 = packh2(ra, rc);
  unsigned h23 = splitpair_h(v.z, v.w, ra, rc);
  unsigned m23 = packh2(ra, rc);
  uint2 H, M;
  H.x = h01; H.y = h23;
  M.x = m01; M.y = m23;
  *(uint2*)hi = H;
  *(uint2*)mid = M;
}

__device__ __forceinline__ void split1(float o, short& h, short& m) {
  _Float16 hf = (_Float16)o;
  _Float16 mf = (_Float16)(o - (float)hf);
  h = __builtin_bit_cast(short, hf);
  m = __builtin_bit_cast(short, mf);
}

__device__ __forceinline__ float h2f(short s) {
  return (float)__builtin_bit_cast(_Float16, s);
}

// ---------------- small kernels ----------------

__global__ __launch_bounds__(256) void k_weights(const float* __restrict__ graph,
                                                 short* __restrict__ Wpl) {
  int row = blockIdx.x;  // b*256 + n
  const float* g = graph + (size_t)row * NSEQ;
  int t = threadIdx.x;
  float v = g[t];
  __shared__ float red[256];
  red[t] = v;
  __syncthreads();
  for (int s = 128; s > 0; s >>= 1) {
    if (t < s) red[t] += red[t + s];
    __syncthreads();
  }
  float w = v / (red[0] + EPSV);
  short h, m;
  split1(w, h, m);
  Wpl[(size_t)row * NSEQ + t] = h;
  Wpl[PSW + (size_t)row * NSEQ + t] = m;
}

__global__ __launch_bounds__(256) void k_colw(const short* __restrict__ Wpl,
                                              float* __restrict__ colw) {
  int b = blockIdx.x;
  int j = threadIdx.x;
  const short* wh = Wpl + (size_t)b * 65536 + j;
  float s = 0.f;
  for (int n = 0; n < NSEQ; n++)
    s += h2f(wh[(size_t)n * NSEQ]) + h2f(wh[PSW + (size_t)n * NSEQ]);
  colw[b * NSEQ + j] = s;
}

__global__ __launch_bounds__(384) void k_wmean(const float* __restrict__ colw,
                                               const float* __restrict__ tokens,
                                               float* __restrict__ wm) {
  int b = blockIdx.x;
  int d = threadIdx.x;
  const float* t = tokens + (size_t)b * NSEQ * DI + d;
  const float* cw = colw + b * NSEQ;
  float s = 0.f;
  for (int n = 0; n < NSEQ; n++) s += cw[n] * t[(size_t)n * DI];
  wm[b * DI + d] = s;
}

// ZT planes: zt[b][d][n] = tokens[b][n][d] - wm[b][d]  (hi/mid fp16)
__global__ __launch_bounds__(256) void k_zcT(const float* __restrict__ tokens,
                                             const float* __restrict__ wm,
                                             short* __restrict__ ZTpl) {
  int b = blockIdx.z;
  int d0 = blockIdx.x * 64, n0 = blockIdx.y * 64;
  __shared__ float ld[64][68];
  const float* Tb = tokens + (size_t)b * NSEQ * DI;
  const float* wmb = wm + (size_t)b * DI;
  short* Zb = ZTpl + (size_t)b * 98304;
#pragma unroll
  for (int i = 0; i < 4; i++) {
    int sl = threadIdx.x + i * 256;
    int r = sl >> 4, q = sl & 15;
    float4 v = *(const float4*)&Tb[(size_t)(n0 + r) * DI + d0 + q * 4];
    float4 m = *(const float4*)&wmb[d0 + q * 4];
    v.x -= m.x; v.y -= m.y; v.z -= m.z; v.w -= m.w;
    *(float4*)&ld[r][q * 4] = v;
  }
  __syncthreads();
#pragma unroll
  for (int i = 0; i < 4; i++) {
    int sl = threadIdx.x + i * 256;
    int dl = sl >> 4, q = sl & 15;
    float4 v;
    v.x = ld[q * 4 + 0][dl];
    v.y = ld[q * 4 + 1][dl];
    v.z = ld[q * 4 + 2][dl];
    v.w = ld[q * 4 + 3][dl];
    size_t off = (size_t)(d0 + dl) * NSEQ + n0 + q * 4;
    split4_store(v, Zb + off, Zb + PSZ + off);
  }
}

__global__ __launch_bounds__(256) void k_trace(const float* __restrict__ M2,
                                               float* __restrict__ tr) {
  int b = blockIdx.x;
  int t = threadIdx.x;
  float s = 0.f;
  for (int d = t; d < DI; d += 256)
    s += M2[(size_t)b * DI * DI + (size_t)d * DI + d];
  __shared__ float red[256];
  red[t] = s;
  __syncthreads();
  for (int st = 128; st > 0; st >>= 1) {
    if (t < st) red[t] += red[t + st];
    __syncthreads();
  }
  if (t == 0) tr[b] = red[0];
}

// MnN planes = split(M2/(tr+eps)); MnT planes = transpose thereof
__global__ __launch_bounds__(256) void k_scaleT(const float* __restrict__ M2,
                                                const float* __restrict__ tr,
                                                short* __restrict__ MnN,
                                                short* __restrict__ MnT) {
  int b = blockIdx.z;
  int c0 = blockIdx.x * 64, r0 = blockIdx.y * 64;
  __shared__ float ld[64][68];
  float inv = 1.0f / (tr[b] + EPSV);
  const float* Xb = M2 + (size_t)b * 147456;
  short* Nb = MnN + (size_t)b * 147456;
  short* Tb = MnT + (size_t)b * 147456;
#pragma unroll
  for (int i = 0; i < 4; i++) {
    int sl = threadIdx.x + i * 256;
    int r = sl >> 4, q = sl & 15;
    float4 v = *(const float4*)&Xb[(size_t)(r0 + r) * 384 + c0 + q * 4];
    v.x *= inv; v.y *= inv; v.z *= inv; v.w *= inv;
    *(float4*)&ld[r][q * 4] = v;
    size_t off = (size_t)(r0 + r) * 384 + c0 + q * 4;
    split4_store(v, Nb + off, Nb + PS3 + off);
  }
  __syncthreads();
#pragma unroll
  for (int i = 0; i < 4; i++) {
    int sl = threadIdx.x + i * 256;
    int n = sl >> 4, q = sl & 15;
    float4 v;
    v.x = ld[q * 4 + 0][n];
    v.y = ld[q * 4 + 1][n];
    v.z = ld[q * 4 + 2][n];
    v.w = ld[q * 4 + 3][n];
    size_t off = (size_t)(c0 + n) * 384 + r0 + q * 4;
    split4_store(v, Tb + off, Tb + PS3 + off);
  }
}

// plane-pair 384x384 fp16 transpose (exact short moves)
__global__ __launch_bounds__(256) void k_transposeP(const short* __restrict__ X,
                                                    short* __restrict__ XT) {
  int b = blockIdx.z;
  int c0 = blockIdx.x * 64, r0 = blockIdx.y * 64;
  __shared__ short ld[64][68];
#pragma unroll
  for (int p = 0; p < 2; p++) {
    const short* Xb = X + (size_t)p * PS3 + (size_t)b * 147456;
    short* Tb = XT + (size_t)p * PS3 + (size_t)b * 147456;
#pragma unroll
    for (int i = 0; i < 2; i++) {
      int sl = threadIdx.x + i * 256;
      int r = sl >> 3, qq = sl & 7;
      *(s16x8*)&ld[r][qq * 8] = *(const s16x8*)&Xb[(size_t)(r0 + r) * 384 + c0 + qq * 8];
    }
    __syncthreads();
#pragma unroll
    for (int i = 0; i < 2; i++) {
      int sl = threadIdx.x + i * 256;
      int n = sl >> 3, qq = sl & 7;
      s16x8 v;
#pragma unroll
      for (int j = 0; j < 8; j++) v[j] = ld[qq * 8 + j][n];
      *(s16x8*)&Tb[(size_t)(c0 + n) * 384 + r0 + qq * 8] = v;
    }
    __syncthreads();
  }
}

// ---------------- pre-split fp16-plane MFMA NT-GEMM -------------------------
// C[m][n] = sum_k A[m][k]*BT[n][k]; A,B are hi/mid fp16 plane pairs; 3 passes
// (hh, hm, mh). No split VALU in the loop. 64x128 tile, XCD swizzle, (256,2).

__device__ __forceinline__ int swzoff(int row, int s) {
  return (((row << 2) + s) ^ (row & 7)) << 3;  // in shorts
}

__device__ __forceinline__ f16x8 ldfrag(const short* p) {
  s16x8 t = *(const s16x8*)p;
  return __builtin_bit_cast(f16x8, t);
}

// MODE 0: fp32 C = alpha*acc + diagAdd*I
// MODE 3: plane C = split(alpha*acc + diagAdd*I)
// MODE 1: Y2T planes epilogue (reads MnN planes via pMnPl/psA, P1T planes via
//         pP1Pl/psB; writes transposed planes via pCh/psC)
// MODE 2: V = triu(alpha*acc)/sqrt(tr+eps), packed fp32 at b*SID
template <int MODE>
__global__ __launch_bounds__(256, 2) void gemm_pre(
    const short* __restrict__ pA, const short* __restrict__ pBT,
    float* __restrict__ pCf, short* __restrict__ pCh,
    const short* __restrict__ pMnPl, const short* __restrict__ pP1Pl,
    const float* __restrict__ trv, int K, int lda, int ldb, int ldc, long sA,
    long sB, long sC, int psA, int psB, int psC, float alpha, float diagAdd,
    int ntn, int ntile) {
  __shared__ short As[2 * 64 * 32];   // 8 KB
  __shared__ short Bs[2 * 128 * 32];  // 16 KB
  int flat = blockIdx.x;
  int q = flat >> 3;
  int b = (flat & 7) + (q / ntile) * 8;
  int tk = q % ntile;
  int m0 = (tk / ntn) * 64;
  int n0 = (tk % ntn) * 128;
  int tid = threadIdx.x;
  int lane = tid & 63, wid = tid >> 6;
  int wm = wid >> 1, wn = wid & 1;
  int lr = lane & 15, lg = lane >> 4;
  int rowA = tid >> 2, subA = tid & 3;
  int rowB = tid >> 1, subB = tid & 1;
  int oA = swzoff(rowA, subA);
  int oB0 = swzoff(rowB, 2 * subB), oB1 = swzoff(rowB, 2 * subB + 1);
  const short* AptrH = pA + (size_t)b * sA + (size_t)(m0 + rowA) * lda + subA * 8;
  const short* AptrM = AptrH + psA;
  const short* BptrH = pBT + (size_t)b * sB + (size_t)(n0 + rowB) * ldb + subB * 16;
  const short* BptrM = BptrH + psB;
  f32x4 acc[2][4] = {};
  s16x8 raH, raM, rbH0, rbH1, rbM0, rbM1;

  raH = *(const s16x8*)(AptrH);
  raM = *(const s16x8*)(AptrM);
  rbH0 = *(const s16x8*)(BptrH);
  rbH1 = *(const s16x8*)(BptrH + 8);
  rbM0 = *(const s16x8*)(BptrM);
  rbM1 = *(const s16x8*)(BptrM + 8);
  *(s16x8*)(As + oA) = raH;
  *(s16x8*)(As + 2048 + oA) = raM;
  *(s16x8*)(Bs + oB0) = rbH0;
  *(s16x8*)(Bs + oB1) = rbH1;
  *(s16x8*)(Bs + 4096 + oB0) = rbM0;
  *(s16x8*)(Bs + 4096 + oB1) = rbM1;
  __syncthreads();

  for (int k0 = 0; k0 < K; k0 += 32) {
    bool more = (k0 + 32) < K;
    if (more) {
      raH = *(const s16x8*)(AptrH + k0 + 32);
      raM = *(const s16x8*)(AptrM + k0 + 32);
      rbH0 = *(const s16x8*)(BptrH + k0 + 32);
      rbH1 = *(const s16x8*)(BptrH + k0 + 40);
      rbM0 = *(const s16x8*)(BptrM + k0 + 32);
      rbM1 = *(const s16x8*)(BptrM + k0 + 40);
    }
#pragma unroll
    for (int ib = 0; ib < 2; ib++) {
      f16x8 bfr[4];
#pragma unroll
      for (int ni = 0; ni < 4; ni++)
        bfr[ni] = ldfrag(Bs + ib * 4096 + swzoff(wn * 64 + ni * 16 + lr, lg));
#pragma unroll
      for (int ia = 0; ia < 2; ia++) {
        if (ia + ib > 1) continue;
        f16x8 afr[2];
#pragma unroll
        for (int mi = 0; mi < 2; mi++)
          afr[mi] = ldfrag(As + ia * 2048 + swzoff(wm * 32 + mi * 16 + lr, lg));
#pragma unroll
        for (int ni = 0; ni < 4; ni++)
#pragma unroll
          for (int mi = 0; mi < 2; mi++)
            acc[mi][ni] = __builtin_amdgcn_mfma_f32_16x16x32_f16(
                afr[mi], bfr[ni], acc[mi][ni], 0, 0, 0);
      }
    }
    __syncthreads();
    if (more) {
      *(s16x8*)(As + oA) = raH;
      *(s16x8*)(As + 2048 + oA) = raM;
      *(s16x8*)(Bs + oB0) = rbH0;
      *(s16x8*)(Bs + oB1) = rbH1;
      *(s16x8*)(Bs + 4096 + oB0) = rbM0;
      *(s16x8*)(Bs + 4096 + oB1) = rbM1;
    }
    __syncthreads();
  }

  const size_t cb = (size_t)b * sC;
  float invs = 0.f;
  if (MODE == 2) invs = 1.0f / sqrtf(trv[b] + EPSV);
#pragma unroll
  for (int mi = 0; mi < 2; mi++)
#pragma unroll
    for (int ni = 0; ni < 4; ni++)
#pragma unroll
      for (int j = 0; j < 4; j++) {
        int row = m0 + wm * 32 + mi * 16 + lg * 4 + j;
        int col = n0 + wn * 64 + ni * 16 + lr;
        float v = acc[mi][ni][j];
        if (MODE == 0) {
          float o = alpha * v;
          if (row == col) o += diagAdd;
          pCf[cb + (size_t)row * ldc + col] = o;
        } else if (MODE == 3) {
          float o = alpha * v;
          if (row == col) o += diagAdd;
          short h, m;
          split1(o, h, m);
          pCh[cb + (size_t)row * ldc + col] = h;
          pCh[cb + psC + (size_t)row * ldc + col] = m;
        } else if (MODE == 1) {
          size_t inm = cb + (size_t)row * 384 + col;
          size_t ip1 = cb + (size_t)col * 384 + row;
          float mn = h2f(pMnPl[inm]) + h2f(pMnPl[psA + inm]);
          float p1 = h2f(pP1Pl[ip1]) + h2f(pP1Pl[psB + ip1]);
          float y2 = -1.875f * mn + 0.75f * p1 - 0.125f * v;
          if (row == col) y2 += 2.25f;
          short h, m;
          split1(y2, h, m);
          pCh[cb + (size_t)col * 384 + row] = h;
          pCh[cb + psC + (size_t)col * 384 + row] = m;
        } else {
          if (col >= row) {
            long idx = (long)b * SID + (long)row * 384 - (long)row * (row - 1) / 2 +
                       (col - row);
            pCf[idx] = alpha * v * invs;
          }
        }
      }
}

// ---------------- FC: part[kc] = V @ W2 (320-k chunk), fp16 2-plane MFMA ----
#define FC_NCH 231

__device__ __forceinline__ void split8_h(f32x4 v0, f32x4 v1, short* dst0, int ps) {
  unsigned h0, h1, h2, h3, m0, m1, m2, m3;
  float ra, rc;
  h0 = splitpair_h(v0[0], v0[1], ra, rc); m0 = packh2(ra, rc);
  h1 = splitpair_h(v0[2], v0[3], ra, rc); m1 = packh2(ra, rc);
  h2 = splitpair_h(v1[0], v1[1], ra, rc); m2 = packh2(ra, rc);
  h3 = splitpair_h(v1[2], v1[3], ra, rc); m3 = packh2(ra, rc);
  uint4 H, M;
  H.x = h0; H.y = h1; H.z = h2; H.w = h3;
  M.x = m0; M.y = m1; M.z = m2; M.w = m3;
  *(uint4*)(dst0) = H;
  *(uint4*)(dst0 + ps) = M;
}

__global__ __launch_bounds__(256, 2) void k_fc(const float* __restrict__ V,
                                               const float* __restrict__ W2,
                                               float* __restrict__ part) {
  __shared__ short As[2 * 64 * 32];
  __shared__ short Bs[2 * 128 * 32];
  int n0 = blockIdx.x * 128;
  int kc = blockIdx.y;
  int tid = threadIdx.x;
  int lane = tid & 63, wid = tid >> 6;
  int wm = wid >> 1, wn = wid & 1;
  int lr = lane & 15, lg = lane >> 4;
  int rowA = tid >> 2, subA = tid & 3;
  int oA = swzoff(rowA, subA);
  int nB = tid >> 1, kh = tid & 1;
  int oB0 = swzoff(nB, 2 * kh), oB1 = swzoff(nB, 2 * kh + 1);
  const float* Aptr = V + (size_t)rowA * SID + kc * 320 + subA * 8;
  const float* Bptr = W2 + (size_t)(kc * 320 + kh * 16) * DOUT + n0 + nB;
  f32x4 acc[2][4] = {};
  f32x4 a0, a1, w0, w1, w2, w3;

#define FC_LOADB(off)                                                       \
  {                                                                         \
    const float* bp = Bptr + (size_t)(off) * DOUT;                          \
    w0[0] = bp[0 * DOUT];  w0[1] = bp[1 * DOUT];                            \
    w0[2] = bp[2 * DOUT];  w0[3] = bp[3 * DOUT];                            \
    w1[0] = bp[4 * DOUT];  w1[1] = bp[5 * DOUT];                            \
    w1[2] = bp[6 * DOUT];  w1[3] = bp[7 * DOUT];                            \
    w2[0] = bp[8 * DOUT];  w2[1] = bp[9 * DOUT];                            \
    w2[2] = bp[10 * DOUT]; w2[3] = bp[11 * DOUT];                           \
    w3[0] = bp[12 * DOUT]; w3[1] = bp[13 * DOUT];                           \
    w3[2] = bp[14 * DOUT]; w3[3] = bp[15 * DOUT];                           \
  }

  a0 = *(const f32x4*)(Aptr + 0);
  a1 = *(const f32x4*)(Aptr + 4);
  FC_LOADB(0);
  split8_h(a0, a1, As + oA, 2048);
  split8_h(w0, w1, Bs + oB0, 4096);
  split8_h(w2, w3, Bs + oB1, 4096);
  __syncthreads();

  for (int st = 0; st < 10; st++) {
    bool more = st < 9;
    if (more) {
      a0 = *(const f32x4*)(Aptr + (st + 1) * 32);
      a1 = *(const f32x4*)(Aptr + (st + 1) * 32 + 4);
      FC_LOADB((st + 1) * 32);
    }
#pragma unroll
    for (int ib = 0; ib < 2; ib++) {
      f16x8 bfr[4];
#pragma unroll
      for (int ni = 0; ni < 4; ni++)
        bfr[ni] = ldfrag(Bs + ib * 4096 + swzoff(wn * 64 + ni * 16 + lr, lg));
#pragma unroll
      for (int ia = 0; ia < 2; ia++) {
        if (ia + ib > 1) continue;
        f16x8 afr[2];
#pragma unroll
        for (int mi = 0; mi < 2; mi++)
          afr[mi] = ldfrag(As + ia * 2048 + swzoff(wm * 32 + mi * 16 + lr, lg));
#pragma unroll
        for (int ni = 0; ni < 4; ni++)
#pragma unroll
          for (int mi = 0; mi < 2; mi++)
            acc[mi][ni] = __builtin_amdgcn_mfma_f32_16x16x32_f16(
                afr[mi], bfr[ni], acc[mi][ni], 0, 0, 0);
      }
    }
    __syncthreads();
    if (more) {
      split8_h(a0, a1, As + oA, 2048);
      split8_h(w0, w1, Bs + oB0, 4096);
      split8_h(w2, w3, Bs + oB1, 4096);
    }
    __syncthreads();
  }

  float* p = part + (size_t)kc * (BB * DOUT) + n0;
#pragma unroll
  for (int mi = 0; mi < 2; mi++)
#pragma unroll
    for (int ni = 0; ni < 4; ni++)
#pragma unroll
      for (int j = 0; j < 4; j++)
        p[(size_t)(wm * 32 + mi * 16 + lg * 4 + j) * DOUT + wn * 64 + ni * 16 + lr] =
            acc[mi][ni][j];
}

__global__ __launch_bounds__(256) void k_reduce(const float* __restrict__ part,
                                                const float* __restrict__ b2,
                                                float* __restrict__ out) {
  int idx = blockIdx.x * 256 + threadIdx.x;
  int c = idx & (DOUT - 1);
  float s = 0.f;
  for (int kc = 0; kc < FC_NCH; kc++) s += part[(size_t)kc * BB * DOUT + idx];
  float x = s + b2[c];
  out[idx] = 0.5f * x * (1.0f + erff(x * 0.70710678118654752f));
}

// ---------------- launch ----------------

extern "C" void kernel_launch(void* const* d_in, const int* in_sizes, int n_in,
                              void* d_out, int out_size, void* d_ws, size_t ws_size,
                              hipStream_t stream) {
  (void)in_sizes; (void)n_in; (void)out_size; (void)ws_size;
  const float* tokens = (const float*)d_in[0];
  const float* graph = (const float*)d_in[1];
  const float* W2 = (const float*)d_in[2];
  const float* b2 = (const float*)d_in[3];

  float* ws = (float*)d_ws;
  const long NM = 9437184L;  // 64*384*384 floats per slot
  float* s0f = ws;            // Wpl -> M2 -> P1Tpl -> TTpl -> part
  float* s1f = ws + NM;       // ZTpl -> MnNpl -> Y2Npl
  float* s2f = ws + 2 * NM;   // WZTpl -> MnTpl -> Y2Tpl -> V
  short* s0h = (short*)s0f;
  short* s1h = (short*)s1f;
  short* s2h = (short*)s2f;
  float* colw = ws + 3 * NM;
  float* wmv = colw + BB * NSEQ;
  float* trv = wmv + BB * DI;

  k_weights<<<BB * NSEQ, 256, 0, stream>>>(graph, s0h);                // W planes
  k_colw<<<BB, 256, 0, stream>>>(s0h, colw);
  k_wmean<<<BB, 384, 0, stream>>>(colw, tokens, wmv);
  k_zcT<<<dim3(6, 4, BB), 256, 0, stream>>>(tokens, wmv, s1h);         // ZT planes

  // WZT planes = NT(ZT, W): M=384,N=256,K=256 -> s2
  gemm_pre<3><<<12 * BB, 256, 0, stream>>>(
      s1h, s0h, nullptr, s2h, nullptr, nullptr, nullptr, 256, 256, 256, 256,
      98304L, 65536L, 98304L, PSZ, PSW, PSZ, 1.f, 0.f, 2, 12);
  // M2 fp32 = NT(ZT, WZT): M=N=384,K=256 -> s0
  gemm_pre<0><<<18 * BB, 256, 0, stream>>>(
      s1h, s2h, s0f, nullptr, nullptr, nullptr, nullptr, 256, 256, 256, 384,
      98304L, 98304L, 147456L, PSZ, PSZ, 0, 1.f, 0.f, 3, 18);

  k_trace<<<BB, 256, 0, stream>>>(s0f, trv);
  k_scaleT<<<dim3(6, 6, BB), 256, 0, stream>>>(s0f, trv, s1h, s2h);    // MnN, MnT planes

  // P1T planes = NT(MnT, MnN) -> s0
  gemm_pre<3><<<18 * BB, 256, 0, stream>>>(
      s2h, s1h, nullptr, s0h, nullptr, nullptr, nullptr, 384, 384, 384, 384,
      147456L, 147456L, 147456L, PS3, PS3, PS3, 1.f, 0.f, 3, 18);
  // H = NT(MnN, P1T); MODE1 epilogue -> Y2T planes -> s2
  gemm_pre<1><<<18 * BB, 256, 0, stream>>>(
      s1h, s0h, nullptr, s2h, s1h, s0h, nullptr, 384, 384, 384, 384,
      147456L, 147456L, 147456L, PS3, PS3, PS3, 0.f, 0.f, 3, 18);
  // TT planes = 3I - NT(Y2T, MnN) -> s0
  gemm_pre<3><<<18 * BB, 256, 0, stream>>>(
      s2h, s1h, nullptr, s0h, nullptr, nullptr, nullptr, 384, 384, 384, 384,
      147456L, 147456L, 147456L, PS3, PS3, PS3, -1.f, 3.f, 3, 18);
  // Y2N planes = transpose(Y2T planes) -> s1
  k_transposeP<<<dim3(6, 6, BB), 256, 0, stream>>>(s2h, s1h);
  // V = triu(0.5 * NT(Y2N, TT)) / sqrt(tr+eps) -> s2 (fp32 packed)
  gemm_pre<2><<<18 * BB, 256, 0, stream>>>(
      s1h, s0h, s2f, nullptr, nullptr, nullptr, trv, 384, 384, 384, 384,
      147456L, 147456L, 0L, PS3, PS3, 0, 0.5f, 0.f, 3, 18);

  // part[kc] = V @ W2 chunk; then out = gelu(sum + b2)
  k_fc<<<dim3(4, FC_NCH), 256, 0, stream>>>(s2f, W2, s0f);
  k_reduce<<<(BB * DOUT) / 256, 256, 0, stream>>>(s0f, b2, (float*)d_out);
}

// Round 12
// 365.333 us; speedup vs baseline: 1.0670x; 1.0670x over previous
//
#include <hip/hip_runtime.h>
#include <hip/hip_fp16.h>
#include <math.h>

#define DI 384
#define NSEQ 256
#define BB 64
#define DOUT 512
#define SID 73920
#define EPSV 1e-5f

typedef float f32x4 __attribute__((ext_vector_type(4)));
typedef short s16x8 __attribute__((ext_vector_type(8)));
typedef _Float16 f16x8 __attribute__((ext_vector_type(8)));

// ---------------- small kernels (r10 versions, fp32 intermediates) ----------

__global__ __launch_bounds__(256) void k_weights(const float* __restrict__ graph,
                                                 float* __restrict__ W) {
  int row = blockIdx.x;
  const float* g = graph + (size_t)row * NSEQ;
  float* w = W + (size_t)row * NSEQ;
  int t = threadIdx.x;
  float v = g[t];
  __shared__ float red[256];
  red[t] = v;
  __syncthreads();
  for (int s = 128; s > 0; s >>= 1) {
    if (t < s) red[t] += red[t + s];
    __syncthreads();
  }
  float deg = red[0] + EPSV;
  w[t] = v / deg;
}

__global__ __launch_bounds__(256) void k_colw(const float* __restrict__ W,
                                              float* __restrict__ colw) {
  int b = blockIdx.x;
  int j = threadIdx.x;
  const float* w = W + (size_t)b * NSEQ * NSEQ + j;
  float s = 0.f;
  for (int n = 0; n < NSEQ; n++) s += w[(size_t)n * NSEQ];
  colw[b * NSEQ + j] = s;
}

__global__ __launch_bounds__(384) void k_wmean(const float* __restrict__ colw,
                                               const float* __restrict__ tokens,
                                               float* __restrict__ wm) {
  int b = blockIdx.x;
  int d = threadIdx.x;
  const float* t = tokens + (size_t)b * NSEQ * DI + d;
  const float* cw = colw + b * NSEQ;
  float s = 0.f;
  for (int n = 0; n < NSEQ; n++) s += cw[n] * t[(size_t)n * DI];
  wm[b * DI + d] = s;
}

// ZT[b][d][n] = tokens[b][n][d] - wm[b][d]
__global__ __launch_bounds__(256) void k_zcT(const float* __restrict__ tokens,
                                             const float* __restrict__ wm,
                                             float* __restrict__ ZT) {
  int b = blockIdx.z;
  int d0 = blockIdx.x * 64, n0 = blockIdx.y * 64;
  __shared__ float ld[64][68];
  const float* Tb = tokens + (size_t)b * NSEQ * DI;
  const float* wmb = wm + (size_t)b * DI;
  float* Zb = ZT + (size_t)b * DI * NSEQ;
#pragma unroll
  for (int i = 0; i < 4; i++) {
    int sl = threadIdx.x + i * 256;
    int r = sl >> 4, q = sl & 15;
    float4 v = *(const float4*)&Tb[(size_t)(n0 + r) * DI + d0 + q * 4];
    float4 m = *(const float4*)&wmb[d0 + q * 4];
    v.x -= m.x; v.y -= m.y; v.z -= m.z; v.w -= m.w;
    *(float4*)&ld[r][q * 4] = v;
  }
  __syncthreads();
#pragma unroll
  for (int i = 0; i < 4; i++) {
    int sl = threadIdx.x + i * 256;
    int dl = sl >> 4, q = sl & 15;
    float4 v;
    v.x = ld[q * 4 + 0][dl];
    v.y = ld[q * 4 + 1][dl];
    v.z = ld[q * 4 + 2][dl];
    v.w = ld[q * 4 + 3][dl];
    *(float4*)&Zb[(size_t)(d0 + dl) * NSEQ + n0 + q * 4] = v;
  }
}

__global__ __launch_bounds__(256) void k_trace(const float* __restrict__ M2,
                                               float* __restrict__ tr) {
  int b = blockIdx.x;
  int t = threadIdx.x;
  float s = 0.f;
  for (int d = t; d < DI; d += 256)
    s += M2[(size_t)b * DI * DI + (size_t)d * DI + d];
  __shared__ float red[256];
  red[t] = s;
  __syncthreads();
  for (int st = 128; st > 0; st >>= 1) {
    if (t < st) red[t] += red[t + st];
    __syncthreads();
  }
  if (t == 0) tr[b] = red[0];
}

// MnN = M2/(tr+eps), MnT = transpose(MnN)
__global__ __launch_bounds__(256) void k_scaleT(const float* __restrict__ M2,
                                                const float* __restrict__ tr,
                                                float* __restrict__ MnN,
                                                float* __restrict__ MnT) {
  int b = blockIdx.z;
  int c0 = blockIdx.x * 64, r0 = blockIdx.y * 64;
  __shared__ float ld[64][68];
  float inv = 1.0f / (tr[b] + EPSV);
  const float* Xb = M2 + (size_t)b * 147456;
  float* Nb = MnN + (size_t)b * 147456;
  float* Tb = MnT + (size_t)b * 147456;
#pragma unroll
  for (int i = 0; i < 4; i++) {
    int sl = threadIdx.x + i * 256;
    int r = sl >> 4, q = sl & 15;
    float4 v = *(const float4*)&Xb[(size_t)(r0 + r) * 384 + c0 + q * 4];
    v.x *= inv; v.y *= inv; v.z *= inv; v.w *= inv;
    *(float4*)&ld[r][q * 4] = v;
    *(float4*)&Nb[(size_t)(r0 + r) * 384 + c0 + q * 4] = v;
  }
  __syncthreads();
#pragma unroll
  for (int i = 0; i < 4; i++) {
    int sl = threadIdx.x + i * 256;
    int n = sl >> 4, q = sl & 15;
    float4 v;
    v.x = ld[q * 4 + 0][n];
    v.y = ld[q * 4 + 1][n];
    v.z = ld[q * 4 + 2][n];
    v.w = ld[q * 4 + 3][n];
    *(float4*)&Tb[(size_t)(c0 + n) * 384 + r0 + q * 4] = v;
  }
}

// fp32 batched 384x384 transpose via LDS
__global__ __launch_bounds__(256) void k_transpose(const float* __restrict__ X,
                                                   float* __restrict__ XT) {
  int b = blockIdx.z;
  int c0 = blockIdx.x * 64, r0 = blockIdx.y * 64;
  __shared__ float ld[64][68];
  const float* Xb = X + (size_t)b * 147456;
  float* Tb = XT + (size_t)b * 147456;
#pragma unroll
  for (int i = 0; i < 4; i++) {
    int sl = threadIdx.x + i * 256;
    int r = sl >> 4, q = sl & 15;
    *(float4*)&ld[r][q * 4] = *(const float4*)&Xb[(size_t)(r0 + r) * 384 + c0 + q * 4];
  }
  __syncthreads();
#pragma unroll
  for (int i = 0; i < 4; i++) {
    int sl = threadIdx.x + i * 256;
    int n = sl >> 4, q = sl & 15;
    float4 v;
    v.x = ld[q * 4 + 0][n];
    v.y = ld[q * 4 + 1][n];
    v.z = ld[q * 4 + 2][n];
    v.w = ld[q * 4 + 3][n];
    *(float4*)&Tb[(size_t)(c0 + n) * 384 + r0 + q * 4] = v;
  }
}

// ---------------- fp16 2-plane split helpers --------------------------------

__device__ __forceinline__ int swzoff(int row, int s) {
  return (((row << 2) + s) ^ (row & 7)) << 3;  // in shorts
}

__device__ __forceinline__ unsigned splitpair_h(float a, float c, float& ra,
                                                float& rc) {
  __half2 h = __float22half2_rn(make_float2(a, c));
  unsigned u;
  __builtin_memcpy(&u, &h, 4);
  ra = a - __low2float(h);
  rc = c - __high2float(h);
  return u;
}

__device__ __forceinline__ unsigned packh2(float a, float c) {
  __half2 h = __float22half2_rn(make_float2(a, c));
  unsigned u;
  __builtin_memcpy(&u, &h, 4);
  return u;
}

// split 8 fp32 -> hi/mid f16x8 planes at dst0 / dst0+ps
__device__ __forceinline__ void split8_h(f32x4 v0, f32x4 v1, short* dst0, int ps) {
  unsigned h0, h1, h2, h3, m0, m1, m2, m3;
  float ra, rc;
  h0 = splitpair_h(v0[0], v0[1], ra, rc); m0 = packh2(ra, rc);
  h1 = splitpair_h(v0[2], v0[3], ra, rc); m1 = packh2(ra, rc);
  h2 = splitpair_h(v1[0], v1[1], ra, rc); m2 = packh2(ra, rc);
  h3 = splitpair_h(v1[2], v1[3], ra, rc); m3 = packh2(ra, rc);
  uint4 H, M;
  H.x = h0; H.y = h1; H.z = h2; H.w = h3;
  M.x = m0; M.y = m1; M.z = m2; M.w = m3;
  *(uint4*)(dst0) = H;
  *(uint4*)(dst0 + ps) = M;
}

__device__ __forceinline__ f16x8 ldfrag(const short* p) {
  s16x8 t = *(const s16x8*)p;
  return __builtin_bit_cast(f16x8, t);
}

// ---------------- fp16-split MFMA NT-GEMM -----------------------------------
// 128x128 block tile, 64x64 per wave (r11 post-mortem: r10's 32x64/wave was
// LDS-read-bound at 0.58 ds_read/MFMA; 64x64 -> 0.33 and 3x longer MFMA
// stretches per k-step). 32 KB LDS, in-loop split (VALU pipe overlaps MFMA),
// XCD-aware swizzle, (256,2) bounds (r6: tighter cap spills prefetch state).

// MODE 0: C = alpha*acc + diagAdd*I (ldc=384)
// MODE 1: Y2T epilogue (reads pMn, pP1T; writes transposed)
// MODE 2: V = triu(alpha*acc)/sqrt(tr+eps), packed per batch (b*SID)
template <int MODE>
__global__ __launch_bounds__(256, 2) void gemm_nt(
    const float* __restrict__ pA, const float* __restrict__ pBT,
    float* __restrict__ pC, const float* __restrict__ pMn,
    const float* __restrict__ pP1T, const float* __restrict__ trv, int K, int lda,
    int ldb, long sA, long sB, long sC, float alpha, float diagAdd, int ntn,
    int ntile) {
  __shared__ short As[2 * 128 * 32];  // 16 KB (hi, mid planes)
  __shared__ short Bs[2 * 128 * 32];  // 16 KB
  int flat = blockIdx.x;
  int q = flat >> 3;
  int b = (flat & 7) + (q / ntile) * 8;
  int tk = q % ntile;
  int m0 = (tk / ntn) * 128;
  int n0 = (tk % ntn) * 128;
  int tid = threadIdx.x;
  int lane = tid & 63, wid = tid >> 6;
  int wm = wid >> 1, wn = wid & 1;
  int lr = lane & 15, lg = lane >> 4;
  int row = tid >> 1, sub = tid & 1;  // staging: 2 threads/row, 16 floats each
  int o0 = swzoff(row, 2 * sub), o1 = swzoff(row, 2 * sub + 1);
  const float* Aptr = pA + (size_t)b * sA + (size_t)(m0 + row) * lda + sub * 16;
  const float* Bptr = pBT + (size_t)b * sB + (size_t)(n0 + row) * ldb + sub * 16;
  f32x4 acc[4][4] = {};
  f32x4 a0, a1, a2, a3, b0, b1, b2, b3;

  a0 = *(const f32x4*)(Aptr + 0);
  a1 = *(const f32x4*)(Aptr + 4);
  a2 = *(const f32x4*)(Aptr + 8);
  a3 = *(const f32x4*)(Aptr + 12);
  b0 = *(const f32x4*)(Bptr + 0);
  b1 = *(const f32x4*)(Bptr + 4);
  b2 = *(const f32x4*)(Bptr + 8);
  b3 = *(const f32x4*)(Bptr + 12);
  split8_h(a0, a1, As + o0, 4096);
  split8_h(a2, a3, As + o1, 4096);
  split8_h(b0, b1, Bs + o0, 4096);
  split8_h(b2, b3, Bs + o1, 4096);
  __syncthreads();

  for (int k0 = 0; k0 < K; k0 += 32) {
    bool more = (k0 + 32) < K;
    if (more) {
      a0 = *(const f32x4*)(Aptr + k0 + 32);
      a1 = *(const f32x4*)(Aptr + k0 + 36);
      a2 = *(const f32x4*)(Aptr + k0 + 40);
      a3 = *(const f32x4*)(Aptr + k0 + 44);
      b0 = *(const f32x4*)(Bptr + k0 + 32);
      b1 = *(const f32x4*)(Bptr + k0 + 36);
      b2 = *(const f32x4*)(Bptr + k0 + 40);
      b3 = *(const f32x4*)(Bptr + k0 + 44);
    }
    // pass 1: hi x hi
    f16x8 ah[4], bh[4];
#pragma unroll
    for (int mi = 0; mi < 4; mi++)
      ah[mi] = ldfrag(As + swzoff(wm * 64 + mi * 16 + lr, lg));
#pragma unroll
    for (int ni = 0; ni < 4; ni++)
      bh[ni] = ldfrag(Bs + swzoff(wn * 64 + ni * 16 + lr, lg));
#pragma unroll
    for (int ni = 0; ni < 4; ni++)
#pragma unroll
      for (int mi = 0; mi < 4; mi++)
        acc[mi][ni] = __builtin_amdgcn_mfma_f32_16x16x32_f16(
            ah[mi], bh[ni], acc[mi][ni], 0, 0, 0);
    // pass 2: hi x mid
    {
      f16x8 bm[4];
#pragma unroll
      for (int ni = 0; ni < 4; ni++)
        bm[ni] = ldfrag(Bs + 4096 + swzoff(wn * 64 + ni * 16 + lr, lg));
#pragma unroll
      for (int ni = 0; ni < 4; ni++)
#pragma unroll
        for (int mi = 0; mi < 4; mi++)
          acc[mi][ni] = __builtin_amdgcn_mfma_f32_16x16x32_f16(
              ah[mi], bm[ni], acc[mi][ni], 0, 0, 0);
    }
    // pass 3: mid x hi
    {
      f16x8 am[4];
#pragma unroll
      for (int mi = 0; mi < 4; mi++)
        am[mi] = ldfrag(As + 4096 + swzoff(wm * 64 + mi * 16 + lr, lg));
#pragma unroll
      for (int ni = 0; ni < 4; ni++)
#pragma unroll
        for (int mi = 0; mi < 4; mi++)
          acc[mi][ni] = __builtin_amdgcn_mfma_f32_16x16x32_f16(
              am[mi], bh[ni], acc[mi][ni], 0, 0, 0);
    }
    __syncthreads();
    if (more) {
      split8_h(a0, a1, As + o0, 4096);
      split8_h(a2, a3, As + o1, 4096);
      split8_h(b0, b1, Bs + o0, 4096);
      split8_h(b2, b3, Bs + o1, 4096);
    }
    __syncthreads();
  }

  const size_t cb = (size_t)b * sC;
  float invs = 0.f;
  if (MODE == 2) invs = 1.0f / sqrtf(trv[b] + EPSV);
#pragma unroll
  for (int mi = 0; mi < 4; mi++)
#pragma unroll
    for (int ni = 0; ni < 4; ni++)
#pragma unroll
      for (int j = 0; j < 4; j++) {
        int rowc = m0 + wm * 64 + mi * 16 + lg * 4 + j;
        int colc = n0 + wn * 64 + ni * 16 + lr;
        float v = acc[mi][ni][j];
        if (MODE == 0) {
          float o = alpha * v;
          if (rowc == colc) o += diagAdd;
          pC[cb + (size_t)rowc * 384 + colc] = o;
        } else if (MODE == 1) {
          float mn = pMn[cb + (size_t)rowc * 384 + colc];
          float p1 = pP1T[cb + (size_t)colc * 384 + rowc];
          float y2 = -1.875f * mn + 0.75f * p1 - 0.125f * v;
          if (rowc == colc) y2 += 2.25f;
          pC[cb + (size_t)colc * 384 + rowc] = y2;  // Y2T
        } else {
          if (colc >= rowc) {
            long idx = (long)b * SID + (long)rowc * 384 -
                       (long)rowc * (rowc - 1) / 2 + (colc - rowc);
            pC[idx] = alpha * v * invs;
          }
        }
      }
}

// ---------------- FC: part[kc] = V @ W2 (320-k chunk), fp16 2-plane MFMA ----
#define FC_NCH 231

__global__ __launch_bounds__(256, 2) void k_fc(const float* __restrict__ V,
                                               const float* __restrict__ W2,
                                               float* __restrict__ part) {
  __shared__ short As[2 * 64 * 32];    // 8 KB
  __shared__ short Bs[2 * 128 * 32];   // 16 KB
  int n0 = blockIdx.x * 128;
  int kc = blockIdx.y;
  int tid = threadIdx.x;
  int lane = tid & 63, wid = tid >> 6;
  int wm = wid >> 1, wn = wid & 1;
  int lr = lane & 15, lg = lane >> 4;
  int rowA = tid >> 2, subA = tid & 3;
  int oA = swzoff(rowA, subA);
  int nB = tid >> 1, kh = tid & 1;
  int oB0 = swzoff(nB, 2 * kh), oB1 = swzoff(nB, 2 * kh + 1);
  const float* Aptr = V + (size_t)rowA * SID + kc * 320 + subA * 8;
  const float* Bptr = W2 + (size_t)(kc * 320 + kh * 16) * DOUT + n0 + nB;
  f32x4 acc[2][4] = {};
  f32x4 a0, a1, w0, w1, w2, w3;

#define FC_LOADB(off)                                                       \
  {                                                                         \
    const float* bp = Bptr + (size_t)(off) * DOUT;                          \
    w0[0] = bp[0 * DOUT];  w0[1] = bp[1 * DOUT];                            \
    w0[2] = bp[2 * DOUT];  w0[3] = bp[3 * DOUT];                            \
    w1[0] = bp[4 * DOUT];  w1[1] = bp[5 * DOUT];                            \
    w1[2] = bp[6 * DOUT];  w1[3] = bp[7 * DOUT];                            \
    w2[0] = bp[8 * DOUT];  w2[1] = bp[9 * DOUT];                            \
    w2[2] = bp[10 * DOUT]; w2[3] = bp[11 * DOUT];                           \
    w3[0] = bp[12 * DOUT]; w3[1] = bp[13 * DOUT];                           \
    w3[2] = bp[14 * DOUT]; w3[3] = bp[15 * DOUT];                           \
  }

  a0 = *(const f32x4*)(Aptr + 0);
  a1 = *(const f32x4*)(Aptr + 4);
  FC_LOADB(0);
  split8_h(a0, a1, As + oA, 2048);
  split8_h(w0, w1, Bs + oB0, 4096);
  split8_h(w2, w3, Bs + oB1, 4096);
  __syncthreads();

  for (int st = 0; st < 10; st++) {
    bool more = st < 9;
    if (more) {
      a0 = *(const f32x4*)(Aptr + (st + 1) * 32);
      a1 = *(const f32x4*)(Aptr + (st + 1) * 32 + 4);
      FC_LOADB((st + 1) * 32);
    }
#pragma unroll
    for (int ib = 0; ib < 2; ib++) {
      f16x8 bfr[4];
#pragma unroll
      for (int ni = 0; ni < 4; ni++)
        bfr[ni] = ldfrag(Bs + ib * 4096 + swzoff(wn * 64 + ni * 16 + lr, lg));
#pragma unroll
      for (int ia = 0; ia < 2; ia++) {
        if (ia + ib > 1) continue;
        f16x8 afr[2];
#pragma unroll
        for (int mi = 0; mi < 2; mi++)
          afr[mi] = ldfrag(As + ia * 2048 + swzoff(wm * 32 + mi * 16 + lr, lg));
#pragma unroll
        for (int ni = 0; ni < 4; ni++)
#pragma unroll
          for (int mi = 0; mi < 2; mi++)
            acc[mi][ni] = __builtin_amdgcn_mfma_f32_16x16x32_f16(
                afr[mi], bfr[ni], acc[mi][ni], 0, 0, 0);
      }
    }
    __syncthreads();
    if (more) {
      split8_h(a0, a1, As + oA, 2048);
      split8_h(w0, w1, Bs + oB0, 4096);
      split8_h(w2, w3, Bs + oB1, 4096);
    }
    __syncthreads();
  }

  float* p = part + (size_t)kc * (BB * DOUT) + n0;
#pragma unroll
  for (int mi = 0; mi < 2; mi++)
#pragma unroll
    for (int ni = 0; ni < 4; ni++)
#pragma unroll
      for (int j = 0; j < 4; j++)
        p[(size_t)(wm * 32 + mi * 16 + lg * 4 + j) * DOUT + wn * 64 + ni * 16 + lr] =
            acc[mi][ni][j];
}

__global__ __launch_bounds__(256) void k_reduce(const float* __restrict__ part,
                                                const float* __restrict__ b2,
                                                float* __restrict__ out) {
  int idx = blockIdx.x * 256 + threadIdx.x;
  int c = idx & (DOUT - 1);
  float s = 0.f;
  for (int kc = 0; kc < FC_NCH; kc++) s += part[(size_t)kc * BB * DOUT + idx];
  float x = s + b2[c];
  out[idx] = 0.5f * x * (1.0f + erff(x * 0.70710678118654752f));
}

// ---------------- launch ----------------

extern "C" void kernel_launch(void* const* d_in, const int* in_sizes, int n_in,
                              void* d_out, int out_size, void* d_ws, size_t ws_size,
                              hipStream_t stream) {
  (void)in_sizes; (void)n_in; (void)out_size; (void)ws_size;
  const float* tokens = (const float*)d_in[0];
  const float* graph = (const float*)d_in[1];
  const float* W2 = (const float*)d_in[2];
  const float* b2 = (const float*)d_in[3];

  float* ws = (float*)d_ws;
  const long NM = 9437184L;  // 64*384*384
  float* s0 = ws;             // W -> M2 -> P1T -> TT
  float* s1 = ws + NM;        // ZT -> MnN -> Y2N -> part
  float* s2 = ws + 2 * NM;    // WZT(ld384) -> MnT -> Y2T -> V(packed)
  float* colw = ws + 3 * NM;
  float* wmv = colw + BB * NSEQ;
  float* trv = wmv + BB * DI;

  k_weights<<<BB * NSEQ, 256, 0, stream>>>(graph, s0);                 // W
  k_colw<<<BB, 256, 0, stream>>>(s0, colw);
  k_wmean<<<BB, 384, 0, stream>>>(colw, tokens, wmv);
  k_zcT<<<dim3(6, 4, BB), 256, 0, stream>>>(tokens, wmv, s1);          // ZT

  // WZT = NT(ZT, W): M=384, N=256, K=256; stored ld=384 in s2
  gemm_nt<0><<<6 * BB, 256, 0, stream>>>(
      s1, s0, s2, nullptr, nullptr, nullptr, 256, 256, 256,
      98304L, 65536L, 147456L, 1.f, 0.f, 2, 6);
  // M2 = NT(ZT, WZT): M=N=384, K=256; WZT read ldb=384
  gemm_nt<0><<<9 * BB, 256, 0, stream>>>(
      s1, s2, s0, nullptr, nullptr, nullptr, 256, 256, 384,
      98304L, 147456L, 147456L, 1.f, 0.f, 3, 9);

  k_trace<<<BB, 256, 0, stream>>>(s0, trv);
  k_scaleT<<<dim3(6, 6, BB), 256, 0, stream>>>(s0, trv, s1, s2);       // MnN, MnT

  // P1T = NT(MnT, MnN) -> s0
  gemm_nt<0><<<9 * BB, 256, 0, stream>>>(s2, s1, s0, nullptr, nullptr, nullptr,
                                         384, 384, 384, 147456L, 147456L, 147456L,
                                         1.f, 0.f, 3, 9);
  // H = NT(MnN, P1T); epilogue writes Y2T -> s2
  gemm_nt<1><<<9 * BB, 256, 0, stream>>>(s1, s0, s2, s1, s0, nullptr,
                                         384, 384, 384, 147456L, 147456L, 147456L,
                                         0.f, 0.f, 3, 9);
  // TT = 3I - NT(Y2T, MnN) -> s0
  gemm_nt<0><<<9 * BB, 256, 0, stream>>>(s2, s1, s0, nullptr, nullptr, nullptr,
                                         384, 384, 384, 147456L, 147456L, 147456L,
                                         -1.f, 3.f, 3, 9);
  // Y2N = transpose(Y2T) -> s1
  k_transpose<<<dim3(6, 6, BB), 256, 0, stream>>>(s2, s1);
  // V = triu(0.5 * NT(Y2N, TT)) / sqrt(tr+eps) -> s2 (packed)
  gemm_nt<2><<<9 * BB, 256, 0, stream>>>(s1, s0, s2, nullptr, nullptr, trv,
                                         384, 384, 384, 147456L, 147456L, 0L,
                                         0.5f, 0.f, 3, 9);

  // part[kc] = V @ W2 chunk; then out = gelu(sum + b2)
  k_fc<<<dim3(4, FC_NCH), 256, 0, stream>>>(s2, W2, s1);
  k_reduce<<<(BB * DOUT) / 256, 256, 0, stream>>>(s1, b2, (float*)d_out);
}